// Round 3
// baseline (270.265 us; speedup 1.0000x reference)
//
#include <hip/hip_runtime.h>
#include <hip/hip_bf16.h>

#define NB   32
#define NT   784
#define NC   768
#define NH   4
#define CH   192
#define PSZ  14
#define NP   196
#define RESO 28
#define EPSV 1e-5f
#define JT   4

// Reference setup_inputs() is jnp.float32 throughout -> fp32 I/O per harness contract.

// ---------------------------------------------------------------------------
// K1: position softmax (H,P,P) + sigmoid gates
// grid = NH*NP blocks of 64; block bid = h*NP + j, softmax over i (axis 0)
// ---------------------------------------------------------------------------
__global__ __launch_bounds__(64) void k_pos(
    const float* __restrict__ pos_w, const float* __restrict__ pos_b,
    const float* __restrict__ mnw,   const float* __restrict__ vnw,
    float* __restrict__ pos_h, float* __restrict__ mwvw) {
  int bid = blockIdx.x;
  int h = bid / NP, j = bid % NP;
  int lane = threadIdx.x;

  if (bid == 0 && lane < 8) {
    float v = (lane < 4) ? mnw[lane] : vnw[lane - 4];
    mwvw[lane] = 1.f / (1.f + expf(-v));
  }

  float w0 = pos_w[h * 3 + 0];
  float w1 = pos_w[h * 3 + 1];
  float w2 = pos_w[h * 3 + 2];
  float pb = pos_b[h];
  int jx = j % PSZ, jy = j / PSZ;

  // pass 1: max
  float mx = -1e30f;
  for (int i = lane; i < NP; i += 64) {
    float ix = (float)(jx - (i % PSZ));
    float iy = (float)(jy - (i / PSZ));
    float s = ix * w0 + iy * w1 + (ix * ix + iy * iy) * w2 + pb;
    mx = fmaxf(mx, s);
  }
  for (int d = 32; d >= 1; d >>= 1) mx = fmaxf(mx, __shfl_down(mx, d, 64));
  mx = __shfl(mx, 0, 64);

  // pass 2: sum of exp
  float sum = 0.f;
  for (int i = lane; i < NP; i += 64) {
    float ix = (float)(jx - (i % PSZ));
    float iy = (float)(jy - (i / PSZ));
    float s = ix * w0 + iy * w1 + (ix * ix + iy * iy) * w2 + pb;
    sum += expf(s - mx);
  }
  for (int d = 32; d >= 1; d >>= 1) sum += __shfl_down(sum, d, 64);
  sum = __shfl(sum, 0, 64);
  float inv = 1.f / sum;

  // pass 3: write normalized
  for (int i = lane; i < NP; i += 64) {
    float ix = (float)(jx - (i % PSZ));
    float iy = (float)(jy - (i / PSZ));
    float s = ix * w0 + iy * w1 + (ix * ix + iy * iy) * w2 + pb;
    pos_h[(size_t)(h * NP + i) * NP + j] = expf(s - mx) * inv;
  }
}

// ---------------------------------------------------------------------------
// K2: group moment2 norm + per-token mean/var(ddof=1) + 2x2 avg pool
// grid = NB*NP blocks of 256; block bid = b*NP + i (patch index)
// Stores rsqrt(m2+eps) per (b,t,h); pooled xn in (B,P,C) layout.
// ---------------------------------------------------------------------------
__global__ __launch_bounds__(256) void k_norm_pool(
    const float* __restrict__ x,
    float* __restrict__ inv_m2, float* __restrict__ mean_ln,
    float* __restrict__ var_ln, float* __restrict__ xp) {
  __shared__ float xl[4][NC];
  __shared__ float invs[16];
  int bid = blockIdx.x;
  int b = bid / NP, i = bid % NP;
  int pr = i / PSZ, pc = i % PSZ;
  int tid = threadIdx.x;

  int trow[4];
#pragma unroll
  for (int k = 0; k < 4; ++k) {
    int dr = k >> 1, dc = k & 1;
    trow[k] = (2 * pr + dr) * RESO + (2 * pc + dc);
  }

  // load 4 token rows
#pragma unroll
  for (int k = 0; k < 4; ++k) {
    const float* row = x + (size_t)(b * NT + trow[k]) * NC;
    for (int c = tid; c < NC; c += 256) xl[k][c] = row[c];
  }
  __syncthreads();

  // m2 per (token, head): 16 groups of 16 lanes, 12 elems each
  {
    int g = tid >> 4, s = tid & 15;
    int k = g >> 2, h = g & 3;
    float acc = 0.f;
#pragma unroll
    for (int m = 0; m < 12; ++m) {
      float v = xl[k][h * CH + s + 16 * m];
      acc += v * v;
    }
    for (int d = 8; d >= 1; d >>= 1) acc += __shfl_down(acc, d, 16);
    if (s == 0) {
      float iv = rsqrtf(acc / (float)CH + EPSV);
      invs[g] = iv;
      inv_m2[(size_t)(b * NT + trow[k]) * NH + h] = iv;
    }
  }
  __syncthreads();

  // normalize in LDS
  for (int idx = tid; idx < 4 * NC; idx += 256) {
    int kk = idx / NC, c = idx % NC;
    xl[kk][c] *= invs[kk * 4 + c / CH];
  }
  __syncthreads();

  // per-token mean / unbiased var over C: 4 groups of 64 lanes
  {
    int k = tid >> 6, s = tid & 63;
    float sm = 0.f, sq = 0.f;
#pragma unroll
    for (int m = 0; m < 12; ++m) {
      float v = xl[k][s + 64 * m];
      sm += v;
      sq += v * v;
    }
    for (int d = 32; d >= 1; d >>= 1) {
      sm += __shfl_down(sm, d, 64);
      sq += __shfl_down(sq, d, 64);
    }
    if (s == 0) {
      float mean = sm / (float)NC;
      mean_ln[b * NT + trow[k]] = mean;
      var_ln[b * NT + trow[k]] = (sq - (float)NC * mean * mean) / (float)(NC - 1);
    }
  }

  // 2x2 pool -> xp (B,P,C)
  for (int c = tid; c < NC; c += 256) {
    float v = (xl[0][c] + xl[1][c] + xl[2][c] + xl[3][c]) * 0.25f;
    xp[(size_t)(b * NP + i) * NC + c] = v;
  }
}

// ---------------------------------------------------------------------------
// K3 (fused einsum + blend + affine + store): grid = NB*(NP/JT) blocks of 256.
// Each block: JT output patches; thread owns channels {tid, tid+256, tid+512}.
// After the i-reduction, directly writes the 4 tokens of each patch.
// ---------------------------------------------------------------------------
__global__ __launch_bounds__(256) void k_einsum_out(
    const float* __restrict__ xp, const float* __restrict__ pos_h,
    const float* __restrict__ x, const float* __restrict__ weight,
    const float* __restrict__ bias, const float* __restrict__ inv_m2,
    const float* __restrict__ mean_ln, const float* __restrict__ var_ln,
    const float* __restrict__ mwvw, float* __restrict__ out) {
  __shared__ float wl[JT][NH * NP];      // 12.5 KB
  __shared__ float tstat[JT][4][6];      // per (patch, token): inv_m2[4], mean, var
  int bid = blockIdx.x;
  int b = bid / (NP / JT), jt = bid % (NP / JT);
  int tid = threadIdx.x;
  int j0 = jt * JT;

  for (int idx = tid; idx < JT * NH * NP; idx += 256) {
    int jj = idx / (NH * NP);
    int rem = idx % (NH * NP);  // h*NP + i
    wl[jj][rem] = pos_h[(size_t)rem * NP + (j0 + jj)];
  }
  // preload per-token stats for the 16 tokens this block will write
  if (tid < JT * 4 * 6) {
    int jj = tid / 24, rem = tid % 24, k = rem / 6, f = rem % 6;
    int j = j0 + jj;
    int t = (2 * (j / PSZ) + (k >> 1)) * RESO + (2 * (j % PSZ) + (k & 1));
    size_t o = (size_t)(b * NT + t);
    tstat[jj][k][f] = (f < 4) ? inv_m2[o * NH + f]
                    : (f == 4) ? mean_ln[o] : var_ln[o];
  }
  __syncthreads();

  int c0 = tid, c1 = tid + 256, c2 = tid + 512;
  int h0 = c0 / CH, h1 = c1 / CH, h2 = c2 / CH;
  float a1[3][JT] = {{0.f}}, a2[3][JT] = {{0.f}};
  const float* base = xp + (size_t)b * NP * NC;

  for (int i = 0; i < NP; ++i) {
    const float* row = base + (size_t)i * NC;
    float v0 = row[c0], v1 = row[c1], v2 = row[c2];
    float q0 = v0 * v0, q1 = v1 * v1, q2 = v2 * v2;
#pragma unroll
    for (int jj = 0; jj < JT; ++jj) {
      float w0 = wl[jj][h0 * NP + i];
      float w1 = wl[jj][h1 * NP + i];
      float w2 = wl[jj][h2 * NP + i];
      a1[0][jj] += w0 * v0; a2[0][jj] += w0 * q0;
      a1[1][jj] += w1 * v1; a2[1][jj] += w1 * q1;
      a1[2][jj] += w2 * v2; a2[2][jj] += w2 * q2;
    }
  }

  // epilogue: blend + affine + store for the 16 tokens
  float wv0 = weight[c0], wv1 = weight[c1], wv2 = weight[c2];
  float bv0 = bias[c0],   bv1 = bias[c1],   bv2 = bias[c2];
  float mw0 = mwvw[h0], mw1 = mwvw[h1], mw2 = mwvw[h2];
  float vw0 = mwvw[4 + h0], vw1 = mwvw[4 + h1], vw2 = mwvw[4 + h2];

#pragma unroll
  for (int jj = 0; jj < JT; ++jj) {
    int j = j0 + jj;
    float m0 = a1[0][jj], m1 = a1[1][jj], m2v = a1[2][jj];
    float p0 = fmaxf(a2[0][jj] - m0 * m0, 0.f);
    float p1 = fmaxf(a2[1][jj] - m1 * m1, 0.f);
    float p2 = fmaxf(a2[2][jj] - m2v * m2v, 0.f);
#pragma unroll
    for (int k = 0; k < 4; ++k) {
      int t = (2 * (j / PSZ) + (k >> 1)) * RESO + (2 * (j % PSZ) + (k & 1));
      size_t xo = (size_t)(b * NT + t) * NC;
      float i0 = tstat[jj][k][h0], i1 = tstat[jj][k][h1], i2 = tstat[jj][k][h2];
      float ml = tstat[jj][k][4], vl = tstat[jj][k][5];

      float xn0 = x[xo + c0] * i0;
      float xn1 = x[xo + c1] * i1;
      float xn2 = x[xo + c2] * i2;

      float mr0 = (1.f - mw0) * m0 + mw0 * ml;
      float mr1 = (1.f - mw1) * m1 + mw1 * ml;
      float mr2 = (1.f - mw2) * m2v + mw2 * ml;
      float vr0 = (1.f - vw0) * p0 + vw0 * vl;
      float vr1 = (1.f - vw1) * p1 + vw1 * vl;
      float vr2 = (1.f - vw2) * p2 + vw2 * vl;

      out[xo + c0] = (xn0 - mr0) * rsqrtf(fmaxf(vr0, 0.f) + EPSV) * wv0 + bv0;
      out[xo + c1] = (xn1 - mr1) * rsqrtf(fmaxf(vr1, 0.f) + EPSV) * wv1 + bv1;
      out[xo + c2] = (xn2 - mr2) * rsqrtf(fmaxf(vr2, 0.f) + EPSV) * wv2 + bv2;
    }
  }
}

// ---------------------------------------------------------------------------
extern "C" void kernel_launch(void* const* d_in, const int* in_sizes, int n_in,
                              void* d_out, int out_size, void* d_ws, size_t ws_size,
                              hipStream_t stream) {
  const float* x     = (const float*)d_in[0];
  const float* wgt   = (const float*)d_in[1];
  const float* bias  = (const float*)d_in[2];
  const float* mnw   = (const float*)d_in[3];
  const float* vnw   = (const float*)d_in[4];
  const float* pos_w = (const float*)d_in[5];
  const float* pos_b = (const float*)d_in[6];
  float* out = (float*)d_out;

  float* ws      = (float*)d_ws;
  float* pos_h   = ws;                              // NH*NP*NP = 153664
  float* mwvw    = pos_h + (size_t)NH * NP * NP;    // 8
  float* inv_m2  = mwvw + 8;                        // NB*NT*NH = 100352
  float* mean_ln = inv_m2 + (size_t)NB * NT * NH;   // 25088
  float* var_ln  = mean_ln + (size_t)NB * NT;       // 25088
  float* xp      = var_ln + (size_t)NB * NT;        // NB*NP*NC = 4816896
  // total ~20.5 MB of workspace

  hipLaunchKernelGGL(k_pos, dim3(NH * NP), dim3(64), 0, stream,
                     pos_w, pos_b, mnw, vnw, pos_h, mwvw);
  hipLaunchKernelGGL(k_norm_pool, dim3(NB * NP), dim3(256), 0, stream,
                     x, inv_m2, mean_ln, var_ln, xp);
  hipLaunchKernelGGL(k_einsum_out, dim3(NB * (NP / JT)), dim3(256), 0, stream,
                     xp, pos_h, x, wgt, bias, inv_m2, mean_ln, var_ln, mwvw, out);
}

// Round 4
// 224.597 us; speedup vs baseline: 1.2033x; 1.2033x over previous
//
#include <hip/hip_runtime.h>
#include <hip/hip_bf16.h>

#define NB   32
#define NT   784
#define NC   768
#define NH   4
#define CH   192
#define PSZ  14
#define NP   196
#define RESO 28
#define EPSV 1e-5f
#define JT   4

// ---------------------------------------------------------------------------
// K1: position softmax -> posT[h][j][i] (transposed for coalesced staging),
// + sigmoid gates. grid = NH*NP blocks of 64; bid = h*NP + j.
// ---------------------------------------------------------------------------
__global__ __launch_bounds__(64) void k_pos(
    const float* __restrict__ pos_w, const float* __restrict__ pos_b,
    const float* __restrict__ mnw,   const float* __restrict__ vnw,
    float* __restrict__ posT, float* __restrict__ mwvw) {
  int bid = blockIdx.x;
  int h = bid / NP, j = bid % NP;
  int lane = threadIdx.x;

  if (bid == 0 && lane < 8) {
    float v = (lane < 4) ? mnw[lane] : vnw[lane - 4];
    mwvw[lane] = 1.f / (1.f + expf(-v));
  }

  float w0 = pos_w[h * 3 + 0];
  float w1 = pos_w[h * 3 + 1];
  float w2 = pos_w[h * 3 + 2];
  float pb = pos_b[h];
  int jx = j % PSZ, jy = j / PSZ;

  float mx = -1e30f;
  for (int i = lane; i < NP; i += 64) {
    float ix = (float)(jx - (i % PSZ));
    float iy = (float)(jy - (i / PSZ));
    float s = ix * w0 + iy * w1 + (ix * ix + iy * iy) * w2 + pb;
    mx = fmaxf(mx, s);
  }
  for (int d = 32; d >= 1; d >>= 1) mx = fmaxf(mx, __shfl_down(mx, d, 64));
  mx = __shfl(mx, 0, 64);

  float sum = 0.f;
  for (int i = lane; i < NP; i += 64) {
    float ix = (float)(jx - (i % PSZ));
    float iy = (float)(jy - (i / PSZ));
    float s = ix * w0 + iy * w1 + (ix * ix + iy * iy) * w2 + pb;
    sum += expf(s - mx);
  }
  for (int d = 32; d >= 1; d >>= 1) sum += __shfl_down(sum, d, 64);
  sum = __shfl(sum, 0, 64);
  float inv = 1.f / sum;

  for (int i = lane; i < NP; i += 64) {
    float ix = (float)(jx - (i % PSZ));
    float iy = (float)(jy - (i / PSZ));
    float s = ix * w0 + iy * w1 + (ix * ix + iy * iy) * w2 + pb;
    posT[((size_t)h * NP + j) * NP + i] = expf(s - mx) * inv;
  }
}

// ---------------------------------------------------------------------------
// K2: wave-per-token group-m2 norm + per-token mean/var + 2x2 pool.
// grid = NB*NP blocks of 256 (4 waves = 4 tokens of one patch).
// Each lane holds 3 float4 (12 channels) in registers; wave-level reductions.
// ---------------------------------------------------------------------------
__global__ __launch_bounds__(256) void k_norm_pool(
    const float* __restrict__ x,
    float* __restrict__ inv_m2, float* __restrict__ mean_ln,
    float* __restrict__ var_ln, float4* __restrict__ xp4) {
  __shared__ float4 xl4[4 * 192];  // 12.3 KB
  int bid = blockIdx.x;
  int b = bid / NP, ip = bid % NP;
  int pr = ip / PSZ, pc = ip % PSZ;
  int tid = threadIdx.x;
  int k = tid >> 6, lane = tid & 63;
  int t = (2 * pr + (k >> 1)) * RESO + (2 * pc + (k & 1));

  const float4* row = (const float4*)(x + (size_t)(b * NT + t) * NC);
  float4 v0 = row[lane], v1 = row[lane + 64], v2 = row[lane + 128];
  // float4 p covers channels 4p..4p+3; head = p/48 (f4-aligned since 48|head size)
  int h0 = lane / 48;            // 0 or 1
  int h1 = (lane + 64) / 48;     // 1 or 2
  int h2 = (lane + 128) / 48;    // 2 or 3

  float d0 = v0.x * v0.x + v0.y * v0.y + v0.z * v0.z + v0.w * v0.w;
  float d1 = v1.x * v1.x + v1.y * v1.y + v1.z * v1.z + v1.w * v1.w;
  float d2 = v2.x * v2.x + v2.y * v2.y + v2.z * v2.z + v2.w * v2.w;
  float s0 = (h0 == 0) ? d0 : 0.f;
  float s1 = ((h0 == 1) ? d0 : 0.f) + ((h1 == 1) ? d1 : 0.f);
  float s2 = ((h1 == 2) ? d1 : 0.f) + ((h2 == 2) ? d2 : 0.f);
  float s3 = (h2 == 3) ? d2 : 0.f;
#pragma unroll
  for (int d = 32; d >= 1; d >>= 1) {
    s0 += __shfl_xor(s0, d, 64);
    s1 += __shfl_xor(s1, d, 64);
    s2 += __shfl_xor(s2, d, 64);
    s3 += __shfl_xor(s3, d, 64);
  }
  float i0 = rsqrtf(s0 * (1.f / CH) + EPSV);
  float i1 = rsqrtf(s1 * (1.f / CH) + EPSV);
  float i2 = rsqrtf(s2 * (1.f / CH) + EPSV);
  float i3 = rsqrtf(s3 * (1.f / CH) + EPSV);
  if (lane < 4) {
    float iv = (lane == 0) ? i0 : (lane == 1) ? i1 : (lane == 2) ? i2 : i3;
    inv_m2[(size_t)(b * NT + t) * NH + lane] = iv;
  }

  float f0 = (h0 == 0) ? i0 : i1;
  float f1 = (h1 == 1) ? i1 : i2;
  float f2 = (h2 == 2) ? i2 : i3;
  v0.x *= f0; v0.y *= f0; v0.z *= f0; v0.w *= f0;
  v1.x *= f1; v1.y *= f1; v1.z *= f1; v1.w *= f1;
  v2.x *= f2; v2.y *= f2; v2.z *= f2; v2.w *= f2;

  float sm = v0.x + v0.y + v0.z + v0.w + v1.x + v1.y + v1.z + v1.w +
             v2.x + v2.y + v2.z + v2.w;
  float sq = v0.x * v0.x + v0.y * v0.y + v0.z * v0.z + v0.w * v0.w +
             v1.x * v1.x + v1.y * v1.y + v1.z * v1.z + v1.w * v1.w +
             v2.x * v2.x + v2.y * v2.y + v2.z * v2.z + v2.w * v2.w;
#pragma unroll
  for (int d = 32; d >= 1; d >>= 1) {
    sm += __shfl_xor(sm, d, 64);
    sq += __shfl_xor(sq, d, 64);
  }
  if (lane == 0) {
    float mean = sm / (float)NC;
    mean_ln[b * NT + t] = mean;
    var_ln[b * NT + t] = (sq - (float)NC * mean * mean) / (float)(NC - 1);
  }

  xl4[k * 192 + lane] = v0;
  xl4[k * 192 + lane + 64] = v1;
  xl4[k * 192 + lane + 128] = v2;
  __syncthreads();

  if (tid < 192) {
    float4 a = xl4[tid], bb = xl4[192 + tid], c = xl4[384 + tid], d = xl4[576 + tid];
    float4 r;
    r.x = (a.x + bb.x + c.x + d.x) * 0.25f;
    r.y = (a.y + bb.y + c.y + d.y) * 0.25f;
    r.z = (a.z + bb.z + c.z + d.z) * 0.25f;
    r.w = (a.w + bb.w + c.w + d.w) * 0.25f;
    xp4[(size_t)(b * NP + ip) * 192 + tid] = r;
  }
}

// ---------------------------------------------------------------------------
// K3: fused einsum + blend + affine + store. grid = NB*(NP/JT) blocks of 256.
// Head-per-wave: wave h owns channels h*192 + lane + 64*{0,1,2} -> weights
// are one ds_read_b128 per (jj, 4 i's).
// ---------------------------------------------------------------------------
__global__ __launch_bounds__(256) void k_einsum_out(
    const float* __restrict__ xp, const float* __restrict__ posT,
    const float* __restrict__ x, const float* __restrict__ weight,
    const float* __restrict__ bias, const float* __restrict__ inv_m2,
    const float* __restrict__ mean_ln, const float* __restrict__ var_ln,
    const float* __restrict__ mwvw, float* __restrict__ out) {
  __shared__ float wl[JT][NH * NP];  // 12.5 KB, [jj][h*196+i]
  __shared__ float tstat[JT][4][6];  // per (patch, token): inv_m2[4], mean, var
  int bid = blockIdx.x;
  int b = bid / (NP / JT), jt = bid % (NP / JT);
  int tid = threadIdx.x;
  int j0 = jt * JT;
  int h = tid >> 6, lane = tid & 63;

#pragma unroll
  for (int jj = 0; jj < JT; ++jj)
#pragma unroll
    for (int hh = 0; hh < NH; ++hh)
      for (int i = tid; i < NP; i += 256)
        wl[jj][hh * NP + i] = posT[((size_t)hh * NP + (j0 + jj)) * NP + i];

  if (tid < JT * 4 * 6) {
    int jj = tid / 24, rem = tid % 24, kk = rem / 6, f = rem % 6;
    int j = j0 + jj;
    int t = (2 * (j / PSZ) + (kk >> 1)) * RESO + (2 * (j % PSZ) + (kk & 1));
    size_t o = (size_t)(b * NT + t);
    tstat[jj][kk][f] = (f < 4) ? inv_m2[o * NH + f]
                     : (f == 4) ? mean_ln[o] : var_ln[o];
  }
  __syncthreads();

  int c0 = h * CH + lane, c1 = c0 + 64, c2 = c0 + 128;
  float a1[3][JT] = {{0.f}}, a2[3][JT] = {{0.f}};
  const float* base = xp + (size_t)b * NP * NC;

  for (int it = 0; it < NP / 4; ++it) {
    float4 w[JT];
#pragma unroll
    for (int jj = 0; jj < JT; ++jj)
      w[jj] = *(const float4*)&wl[jj][h * NP + 4 * it];
#pragma unroll
    for (int u = 0; u < 4; ++u) {
      const float* row = base + (size_t)(4 * it + u) * NC;
      float v0 = row[c0], v1 = row[c1], v2 = row[c2];
      float q0 = v0 * v0, q1 = v1 * v1, q2 = v2 * v2;
#pragma unroll
      for (int jj = 0; jj < JT; ++jj) {
        float ww = (u == 0) ? w[jj].x : (u == 1) ? w[jj].y : (u == 2) ? w[jj].z : w[jj].w;
        a1[0][jj] += ww * v0; a2[0][jj] += ww * q0;
        a1[1][jj] += ww * v1; a2[1][jj] += ww * q1;
        a1[2][jj] += ww * v2; a2[2][jj] += ww * q2;
      }
    }
  }

  // epilogue: blend + affine + store (all channel slots share head h)
  float wv0 = weight[c0], wv1 = weight[c1], wv2 = weight[c2];
  float bv0 = bias[c0],   bv1 = bias[c1],   bv2 = bias[c2];
  float mw = mwvw[h], vw = mwvw[4 + h];

#pragma unroll
  for (int jj = 0; jj < JT; ++jj) {
    int j = j0 + jj;
    float m0 = a1[0][jj], m1 = a1[1][jj], m2v = a1[2][jj];
    float p0 = fmaxf(a2[0][jj] - m0 * m0, 0.f);
    float p1 = fmaxf(a2[1][jj] - m1 * m1, 0.f);
    float p2 = fmaxf(a2[2][jj] - m2v * m2v, 0.f);
#pragma unroll
    for (int kk = 0; kk < 4; ++kk) {
      int t = (2 * (j / PSZ) + (kk >> 1)) * RESO + (2 * (j % PSZ) + (kk & 1));
      size_t xo = (size_t)(b * NT + t) * NC;
      float iv = tstat[jj][kk][h];
      float ml = tstat[jj][kk][4], vl = tstat[jj][kk][5];

      float xn0 = x[xo + c0] * iv;
      float xn1 = x[xo + c1] * iv;
      float xn2 = x[xo + c2] * iv;

      float mr0 = (1.f - mw) * m0 + mw * ml;
      float mr1 = (1.f - mw) * m1 + mw * ml;
      float mr2 = (1.f - mw) * m2v + mw * ml;
      float vr0 = (1.f - vw) * p0 + vw * vl;
      float vr1 = (1.f - vw) * p1 + vw * vl;
      float vr2 = (1.f - vw) * p2 + vw * vl;

      out[xo + c0] = (xn0 - mr0) * rsqrtf(vr0 + EPSV) * wv0 + bv0;
      out[xo + c1] = (xn1 - mr1) * rsqrtf(vr1 + EPSV) * wv1 + bv1;
      out[xo + c2] = (xn2 - mr2) * rsqrtf(vr2 + EPSV) * wv2 + bv2;
    }
  }
}

// ---------------------------------------------------------------------------
extern "C" void kernel_launch(void* const* d_in, const int* in_sizes, int n_in,
                              void* d_out, int out_size, void* d_ws, size_t ws_size,
                              hipStream_t stream) {
  const float* x     = (const float*)d_in[0];
  const float* wgt   = (const float*)d_in[1];
  const float* bias  = (const float*)d_in[2];
  const float* mnw   = (const float*)d_in[3];
  const float* vnw   = (const float*)d_in[4];
  const float* pos_w = (const float*)d_in[5];
  const float* pos_b = (const float*)d_in[6];
  float* out = (float*)d_out;

  float* ws      = (float*)d_ws;
  float* posT    = ws;                              // NH*NP*NP = 153664
  float* mwvw    = posT + (size_t)NH * NP * NP;     // 8
  float* inv_m2  = mwvw + 8;                        // NB*NT*NH = 100352
  float* mean_ln = inv_m2 + (size_t)NB * NT * NH;   // 25088
  float* var_ln  = mean_ln + (size_t)NB * NT;       // 25088
  float* xp      = var_ln + (size_t)NB * NT;        // NB*NP*NC = 4816896 (16B aligned)
  // total ~20.5 MB of workspace

  hipLaunchKernelGGL(k_pos, dim3(NH * NP), dim3(64), 0, stream,
                     pos_w, pos_b, mnw, vnw, posT, mwvw);
  hipLaunchKernelGGL(k_norm_pool, dim3(NB * NP), dim3(256), 0, stream,
                     x, inv_m2, mean_ln, var_ln, (float4*)xp);
  hipLaunchKernelGGL(k_einsum_out, dim3(NB * (NP / JT)), dim3(256), 0, stream,
                     xp, posT, x, wgt, bias, inv_m2, mean_ln, var_ln, mwvw, out);
}